// Round 15
// baseline (16.577 us; speedup 1.0000x reference)
//
#include <hip/hip_runtime.h>
#include <math.h>

#define BB 2048   // batch B
#define NN 512    // classes N
#define DD 256    // dim D

typedef __attribute__((ext_vector_type(8))) _Float16 f16x8;  // 8 f16 (4 VGPRs)
typedef __attribute__((ext_vector_type(4))) float f32x4;

#define MFMA_F16 __builtin_amdgcn_mfma_f32_16x16x32_f16

__device__ __forceinline__ ushort f2h(float f) {             // RNE f32->f16
    union { _Float16 h; ushort u; } c; c.h = (_Float16)f; return c.u;
}
// pack 4 scaled floats into 4 f16 (one uint2)
__device__ __forceinline__ uint2 pack4h(f32x4 v, float s) {
    uint2 r;
    r.x = (unsigned)f2h(v.x * s) | ((unsigned)f2h(v.y * s) << 16);
    r.y = (unsigned)f2h(v.z * s) | ((unsigned)f2h(v.w * s) << 16);
    return r;
}
// stable fast asinh: sign(z) * log(|z| + sqrt(z^2+1))
__device__ __forceinline__ float fast_asinh(float z) {
    float az = fabsf(z);
    float r = __logf(az + sqrtf(fmaf(az, az, 1.0f)));
    return copysignf(r, z);
}
// fast tanh for u >= 0 (our args are in (0, ~1.2]): 1 - 2/(e^{2u}+1).
// __expf -> native v_exp_f32; rel err ~1e-7, negligible through the logit.
__device__ __forceinline__ float fast_tanh(float u) {
    float e = __expf(2.0f * u);
    return 1.0f - 2.0f / (e + 1.0f);
}

// ---------------- K1: one WAVE per row (R14 structure, fast tanh) ----------
// Waves [0,BB): x -> Poincare ball. Waves [BB,BB+NN): p,a -> poincare + scalars.
// All matrices f16, PRE-SWIZZLED: el ^= (row&7)<<3 within each 64-elem chunk.
__global__ __launch_bounds__(256) void hmlr_transform(
    const float* __restrict__ x, const float* __restrict__ a_vals,
    const float* __restrict__ p_vals,
    ushort* __restrict__ Xf, ushort* __restrict__ Pf, ushort* __restrict__ Af,
    float* __restrict__ y2, float* __restrict__ p2s, float* __restrict__ pas,
    float* __restrict__ ans, float* __restrict__ ks)
{
    const int lane = threadIdx.x & 63;
    const int wid  = blockIdx.x * 4 + (threadIdx.x >> 6);   // row id, < BB+NN
    const int e0   = lane * 4;                              // 4 elems per lane

    if (wid < BB) {
        const int r = wid;
        f32x4 v = *(const f32x4*)&x[(size_t)r * DD + e0];
        float ss = v.x * v.x + v.y * v.y + v.z * v.z + v.w * v.w;
        #pragma unroll
        for (int m = 32; m; m >>= 1) ss += __shfl_xor(ss, m, 64);
        float norm0 = sqrtf(ss);
        float fac = fminf(1.0f, 1.0f / (norm0 + 1e-5f));    // CLIP_R = 1
        float u = fmaxf(norm0 * fac, 1e-5f);
        float th = fast_tanh(u);                             // sqrt_c = 1
        float en = fmaxf(th, 1e-5f);
        float wgt = (en > 0.999f) ? (0.999f / en) : 1.0f;    // project
        float s = fac * (th / u) * wgt;                      // x -> xb scale
        if (lane == 0) { float fn = th * wgt; y2[r] = fn * fn; }
        int es = e0 ^ ((r & 7) << 3);                        // pre-swizzle
        *(uint2*)&Xf[(size_t)r * DD + es] = pack4h(v, s);
    } else {
        const int n = wid - BB;
        f32x4 pv = *(const f32x4*)&p_vals[(size_t)n * DD + e0];
        f32x4 av = *(const f32x4*)&a_vals[(size_t)n * DD + e0];
        float sp = pv.x * pv.x + pv.y * pv.y + pv.z * pv.z + pv.w * pv.w;
        float sa = av.x * av.x + av.y * av.y + av.z * av.z + av.w * av.w;
        float sx = pv.x * av.x + pv.y * av.y + pv.z * av.z + pv.w * av.w;
        #pragma unroll
        for (int m = 32; m; m >>= 1) {
            sp += __shfl_xor(sp, m, 64);
            sa += __shfl_xor(sa, m, 64);
            sx += __shfl_xor(sx, m, 64);
        }
        float u = fmaxf(sqrtf(sp), 1e-5f);
        float th = fast_tanh(u);
        float spp = th / u;                                  // p -> p_poincare
        float p2 = th * th;
        float conf = 1.0f - p2;                              // conformal
        if (lane == 0) {
            p2s[n] = p2;
            pas[n] = spp * conf * sx;                        // P . A
            float an = sqrtf(sa) * conf;                     // ||a_poincare||
            ans[n] = an;
            ks[n] = (2.0f / conf) * an;                      // lam * a_norm
        }
        int es = e0 ^ ((n & 7) << 3);
        *(uint2*)&Pf[(size_t)n * DD + es] = pack4h(pv, spp);
        *(uint2*)&Af[(size_t)n * DD + es] = pack4h(av, conf);
    }
}

// ---------------- K2: 64x64 tile, whole-K single-stage, ONE barrier ---------
// (unchanged from R14) Dynamic LDS: [3][64][256] ushort = 96 KiB.
__global__ __launch_bounds__(512) void hmlr_gemm(
    const ushort* __restrict__ Xf, const ushort* __restrict__ Pf,
    const ushort* __restrict__ Af,
    const float* __restrict__ y2, const float* __restrict__ p2s,
    const float* __restrict__ pas, const float* __restrict__ ans,
    const float* __restrict__ ks, float* __restrict__ out)
{
    extern __shared__ ushort T[];          // [3][64][256]

    const int t    = threadIdx.x;
    const int lane = t & 63;
    const int w    = t >> 6;               // wave 0..7
    const int bid  = blockIdx.x;
    // XCD-aware mapping: xcd = bid&7 (dispatch round-robin). All 8 blocks
    // sharing one b0 (same X rows) land on the SAME xcd -> X re-reads L2-hit.
    const int xcd  = bid & 7;
    const int j    = bid >> 3;             // 0..31
    const int b0   = (xcd * 4 + (j >> 3)) * 64;
    const int n0   = (j & 7) * 64;
    const int wr   = w >> 2;               // m half: 32 rows
    const int wc   = w & 3;                // n strip: 16 cols

    const ushort* bases[3] = {Xf, Pf, Af};

    // ---- stage ALL of X/P/A (whole K) into LDS: 96 chunks of 1 KiB ----
    #pragma unroll
    for (int i = 0; i < 12; ++i) {
        int g = w * 12 + i;
        int mat = g >> 5;
        int c = g & 31;
        int grow = (mat == 0 ? b0 : n0) + c * 2 + (lane >> 5);
        const ushort* src = bases[mat] + (size_t)grow * DD + (lane & 31) * 8;
        const ushort* dst = T + ((mat * 64 + c * 2) * 256);
        __builtin_amdgcn_global_load_lds(
            (const __attribute__((address_space(1))) unsigned int*)(const void*)src,
            (__attribute__((address_space(3))) unsigned int*)(void*)dst,
            16, 0, 0);
    }

    const int ram = wr * 32 + (lane & 15);
    const int rbn = wc * 16 + (lane & 15);
    const int ge  = (lane >> 4) * 8;       // elem group within 32-elem k-slice

    // ---- early epilogue-scalar prefetch (overlaps staging) ----
    const int n = n0 + rbn;
    float p2 = p2s[n], pa = pas[n], an = ans[n], kk = ks[n];
    float yv[8];
    #pragma unroll
    for (int m = 0; m < 2; ++m)
        #pragma unroll
        for (int rg = 0; rg < 4; ++rg)
            yv[m * 4 + rg] = y2[b0 + wr * 32 + m * 16 + (lane >> 4) * 4 + rg];
    asm volatile("" :: "v"(p2), "v"(pa), "v"(an), "v"(kk));
    #pragma unroll
    for (int i = 0; i < 8; ++i) asm volatile("" :: "v"(yv[i]));

    __syncthreads();                       // single drain: everything resident

    // ---- GEMM: 8 x {4 swizzled ds_read_b128 + 4 MFMA}, barrier-free ----
    f32x4 axy0 = {0.f,0.f,0.f,0.f}, axy1 = {0.f,0.f,0.f,0.f};
    f32x4 axa0 = {0.f,0.f,0.f,0.f}, axa1 = {0.f,0.f,0.f,0.f};
    const int swzA = (ram & 7) << 3;       // same for ram+16
    const int swzB = (rbn & 7) << 3;
    const ushort* x0r = T + (size_t)ram * 256;
    const ushort* x1r = T + (size_t)(ram + 16) * 256;
    const ushort* pr  = T + (size_t)(64 + rbn) * 256;
    const ushort* ar  = T + (size_t)(128 + rbn) * 256;

    #pragma unroll
    for (int q = 0; q < 8; ++q) {
        int f = q * 32 + ge;
        int pA = f ^ swzA;                 // XOR stays within 64-elem chunk
        int pB = f ^ swzB;
        f16x8 xf0 = *(const f16x8*)(x0r + pA);
        f16x8 xf1 = *(const f16x8*)(x1r + pA);
        f16x8 pf  = *(const f16x8*)(pr + pB);
        f16x8 af  = *(const f16x8*)(ar + pB);
        axy0 = MFMA_F16(xf0, pf, axy0, 0, 0, 0);
        axy1 = MFMA_F16(xf1, pf, axy1, 0, 0, 0);
        axa0 = MFMA_F16(xf0, af, axa0, 0, 0, 0);
        axa1 = MFMA_F16(xf1, af, axa1, 0, 0, 0);
    }

    // Epilogue. C/D map: col = lane&15, row = (lane>>4)*4 + reg.
    #pragma unroll
    for (int m = 0; m < 2; ++m) {
        f32x4 acc_xy = m ? axy1 : axy0;
        f32x4 acc_xa = m ? axa1 : axa0;
        #pragma unroll
        for (int rg = 0; rg < 4; ++rg) {
            int b = b0 + wr * 32 + m * 16 + (lane >> 4) * 4 + rg;
            float yy  = yv[m * 4 + rg];
            float xy  = -acc_xy[rg];                     // (-P).X
            float xa  =  acc_xa[rg];
            float dnm = 1.f + 2.f * xy + p2 * yy + 1e-5f;
            float alpha = (1.f + 2.f * xy + yy) / dnm;   // coeff on (-P)
            float beta  = (1.f - p2) / dnm;              // coeff on X
            float num  = 2.f * (beta * xa - alpha * pa);
            float mob2 = alpha * alpha * p2 + beta * beta * yy
                       + 2.f * alpha * beta * xy;
            float den  = an * (1.f - mob2);
            out[(size_t)b * NN + n] = kk * fast_asinh(num / den);
        }
    }
}

extern "C" void kernel_launch(void* const* d_in, const int* in_sizes, int n_in,
                              void* d_out, int out_size, void* d_ws, size_t ws_size,
                              hipStream_t stream) {
    const float* x      = (const float*)d_in[0];
    const float* a_vals = (const float*)d_in[1];
    const float* p_vals = (const float*)d_in[2];
    float* out = (float*)d_out;

    ushort* Xf = (ushort*)d_ws;                 // [BB][DD] f16 (pre-swizzled)
    ushort* Pf = Xf + (size_t)BB * DD;          // [NN][DD] f16 (pre-swizzled)
    ushort* Af = Pf + (size_t)NN * DD;
    float*  y2  = (float*)(Af + (size_t)NN * DD);
    float*  p2s = y2 + BB;
    float*  pas = p2s + NN;
    float*  ans = pas + NN;
    float*  ks  = ans + NN;

    (void)hipFuncSetAttribute(reinterpret_cast<const void*>(hmlr_gemm),
                              hipFuncAttributeMaxDynamicSharedMemorySize, 98304);

    hipLaunchKernelGGL(hmlr_transform, dim3((BB + NN) / 4), dim3(256), 0, stream,
                       x, a_vals, p_vals, Xf, Pf, Af, y2, p2s, pas, ans, ks);
    hipLaunchKernelGGL(hmlr_gemm, dim3(256), dim3(512), 98304, stream,
                       Xf, Pf, Af, y2, p2s, pas, ans, ks, out);
}

// Round 16
// 16.537 us; speedup vs baseline: 1.0024x; 1.0024x over previous
//
#include <hip/hip_runtime.h>
#include <math.h>

#define BB 2048   // batch B
#define NN 512    // classes N
#define DD 256    // dim D

typedef __attribute__((ext_vector_type(8))) _Float16 f16x8;  // 8 f16 (4 VGPRs)
typedef __attribute__((ext_vector_type(4))) float f32x4;

#define MFMA_F16 __builtin_amdgcn_mfma_f32_16x16x32_f16

__device__ __forceinline__ ushort f2h(float f) {             // RNE f32->f16
    union { _Float16 h; ushort u; } c; c.h = (_Float16)f; return c.u;
}
// pack 4 scaled floats into 4 f16 (one uint2)
__device__ __forceinline__ uint2 pack4h(f32x4 v, float s) {
    uint2 r;
    r.x = (unsigned)f2h(v.x * s) | ((unsigned)f2h(v.y * s) << 16);
    r.y = (unsigned)f2h(v.z * s) | ((unsigned)f2h(v.w * s) << 16);
    return r;
}
// stable fast asinh: sign(z) * log(|z| + sqrt(z^2+1))
__device__ __forceinline__ float fast_asinh(float z) {
    float az = fabsf(z);
    float r = __logf(az + sqrtf(fmaf(az, az, 1.0f)));
    return copysignf(r, z);
}

// ---------------- K1: one WAVE per row ----------------
// Waves [0,BB): x -> Poincare ball. Waves [BB,BB+NN): p,a -> poincare + scalars.
// All matrices f16, PRE-SWIZZLED: el ^= (row&7)<<3 within each 64-elem chunk.
__global__ __launch_bounds__(256) void hmlr_transform(
    const float* __restrict__ x, const float* __restrict__ a_vals,
    const float* __restrict__ p_vals,
    ushort* __restrict__ Xf, ushort* __restrict__ Pf, ushort* __restrict__ Af,
    float* __restrict__ y2, float* __restrict__ p2s, float* __restrict__ pas,
    float* __restrict__ ans, float* __restrict__ ks)
{
    const int lane = threadIdx.x & 63;
    const int wid  = blockIdx.x * 4 + (threadIdx.x >> 6);   // row id, < BB+NN
    const int e0   = lane * 4;                              // 4 elems per lane

    if (wid < BB) {
        const int r = wid;
        f32x4 v = *(const f32x4*)&x[(size_t)r * DD + e0];
        float ss = v.x * v.x + v.y * v.y + v.z * v.z + v.w * v.w;
        #pragma unroll
        for (int m = 32; m; m >>= 1) ss += __shfl_xor(ss, m, 64);
        float norm0 = sqrtf(ss);
        float fac = fminf(1.0f, 1.0f / (norm0 + 1e-5f));    // CLIP_R = 1
        float u = fmaxf(norm0 * fac, 1e-5f);
        float th = tanhf(u);                                 // sqrt_c = 1
        float en = fmaxf(th, 1e-5f);
        float wgt = (en > 0.999f) ? (0.999f / en) : 1.0f;    // project
        float s = fac * (th / u) * wgt;                      // x -> xb scale
        if (lane == 0) { float fn = th * wgt; y2[r] = fn * fn; }
        int es = e0 ^ ((r & 7) << 3);                        // pre-swizzle
        *(uint2*)&Xf[(size_t)r * DD + es] = pack4h(v, s);
    } else {
        const int n = wid - BB;
        f32x4 pv = *(const f32x4*)&p_vals[(size_t)n * DD + e0];
        f32x4 av = *(const f32x4*)&a_vals[(size_t)n * DD + e0];
        float sp = pv.x * pv.x + pv.y * pv.y + pv.z * pv.z + pv.w * pv.w;
        float sa = av.x * av.x + av.y * av.y + av.z * av.z + av.w * av.w;
        float sx = pv.x * av.x + pv.y * av.y + pv.z * av.z + pv.w * av.w;
        #pragma unroll
        for (int m = 32; m; m >>= 1) {
            sp += __shfl_xor(sp, m, 64);
            sa += __shfl_xor(sa, m, 64);
            sx += __shfl_xor(sx, m, 64);
        }
        float u = fmaxf(sqrtf(sp), 1e-5f);
        float th = tanhf(u);
        float spp = th / u;                                  // p -> p_poincare
        float p2 = th * th;
        float conf = 1.0f - p2;                              // conformal
        if (lane == 0) {
            p2s[n] = p2;
            pas[n] = spp * conf * sx;                        // P . A
            float an = sqrtf(sa) * conf;                     // ||a_poincare||
            ans[n] = an;
            ks[n] = (2.0f / conf) * an;                      // lam * a_norm
        }
        int es = e0 ^ ((n & 7) << 3);
        *(uint2*)&Pf[(size_t)n * DD + es] = pack4h(pv, spp);
        *(uint2*)&Af[(size_t)n * DD + es] = pack4h(av, conf);
    }
}

// ---------------- K2: 64x64 tile, whole-K single-stage, ONE barrier ---------
// Dynamic LDS: [3][64][256] ushort = 96 KiB (X, P, A full-K tiles).
// 12 global_load_lds per wave issued at once -> one vmcnt drain -> 8 straight
// k-slices x {4 swizzled ds_read_b128 + 4 MFMA} -> fused asinh epilogue.
__global__ __launch_bounds__(512) void hmlr_gemm(
    const ushort* __restrict__ Xf, const ushort* __restrict__ Pf,
    const ushort* __restrict__ Af,
    const float* __restrict__ y2, const float* __restrict__ p2s,
    const float* __restrict__ pas, const float* __restrict__ ans,
    const float* __restrict__ ks, float* __restrict__ out)
{
    extern __shared__ ushort T[];          // [3][64][256]

    const int t    = threadIdx.x;
    const int lane = t & 63;
    const int w    = t >> 6;               // wave 0..7
    const int bid  = blockIdx.x;
    // XCD-aware mapping: xcd = bid&7 (dispatch round-robin). All 8 blocks
    // sharing one b0 (same X rows) land on the SAME xcd -> X re-reads L2-hit.
    const int xcd  = bid & 7;
    const int j    = bid >> 3;             // 0..31
    const int b0   = (xcd * 4 + (j >> 3)) * 64;
    const int n0   = (j & 7) * 64;
    const int wr   = w >> 2;               // m half: 32 rows
    const int wc   = w & 3;                // n strip: 16 cols

    const ushort* bases[3] = {Xf, Pf, Af};

    // ---- stage ALL of X/P/A (whole K) into LDS: 96 chunks of 1 KiB ----
    // chunk g = w*12+i: mat = g>>5, pair c = g&31 (rows c*2, c*2+1).
    #pragma unroll
    for (int i = 0; i < 12; ++i) {
        int g = w * 12 + i;
        int mat = g >> 5;
        int c = g & 31;
        int grow = (mat == 0 ? b0 : n0) + c * 2 + (lane >> 5);
        const ushort* src = bases[mat] + (size_t)grow * DD + (lane & 31) * 8;
        const ushort* dst = T + ((mat * 64 + c * 2) * 256);
        __builtin_amdgcn_global_load_lds(
            (const __attribute__((address_space(1))) unsigned int*)(const void*)src,
            (__attribute__((address_space(3))) unsigned int*)(void*)dst,
            16, 0, 0);
    }

    const int ram = wr * 32 + (lane & 15);
    const int rbn = wc * 16 + (lane & 15);
    const int ge  = (lane >> 4) * 8;       // elem group within 32-elem k-slice

    // ---- early epilogue-scalar prefetch (overlaps staging) ----
    const int n = n0 + rbn;
    float p2 = p2s[n], pa = pas[n], an = ans[n], kk = ks[n];
    float yv[8];
    #pragma unroll
    for (int m = 0; m < 2; ++m)
        #pragma unroll
        for (int rg = 0; rg < 4; ++rg)
            yv[m * 4 + rg] = y2[b0 + wr * 32 + m * 16 + (lane >> 4) * 4 + rg];
    asm volatile("" :: "v"(p2), "v"(pa), "v"(an), "v"(kk));
    #pragma unroll
    for (int i = 0; i < 8; ++i) asm volatile("" :: "v"(yv[i]));

    __syncthreads();                       // single drain: everything resident

    // ---- GEMM: 8 x {4 swizzled ds_read_b128 + 4 MFMA}, barrier-free ----
    f32x4 axy0 = {0.f,0.f,0.f,0.f}, axy1 = {0.f,0.f,0.f,0.f};
    f32x4 axa0 = {0.f,0.f,0.f,0.f}, axa1 = {0.f,0.f,0.f,0.f};
    const int swzA = (ram & 7) << 3;       // same for ram+16
    const int swzB = (rbn & 7) << 3;
    const ushort* x0r = T + (size_t)ram * 256;
    const ushort* x1r = T + (size_t)(ram + 16) * 256;
    const ushort* pr  = T + (size_t)(64 + rbn) * 256;
    const ushort* ar  = T + (size_t)(128 + rbn) * 256;

    #pragma unroll
    for (int q = 0; q < 8; ++q) {
        int f = q * 32 + ge;
        int pA = f ^ swzA;                 // XOR stays within 64-elem chunk
        int pB = f ^ swzB;
        f16x8 xf0 = *(const f16x8*)(x0r + pA);
        f16x8 xf1 = *(const f16x8*)(x1r + pA);
        f16x8 pf  = *(const f16x8*)(pr + pB);
        f16x8 af  = *(const f16x8*)(ar + pB);
        axy0 = MFMA_F16(xf0, pf, axy0, 0, 0, 0);
        axy1 = MFMA_F16(xf1, pf, axy1, 0, 0, 0);
        axa0 = MFMA_F16(xf0, af, axa0, 0, 0, 0);
        axa1 = MFMA_F16(xf1, af, axa1, 0, 0, 0);
    }

    // Epilogue. C/D map: col = lane&15, row = (lane>>4)*4 + reg.
    #pragma unroll
    for (int m = 0; m < 2; ++m) {
        f32x4 acc_xy = m ? axy1 : axy0;
        f32x4 acc_xa = m ? axa1 : axa0;
        #pragma unroll
        for (int rg = 0; rg < 4; ++rg) {
            int b = b0 + wr * 32 + m * 16 + (lane >> 4) * 4 + rg;
            float yy  = yv[m * 4 + rg];
            float xy  = -acc_xy[rg];                     // (-P).X
            float xa  =  acc_xa[rg];
            float dnm = 1.f + 2.f * xy + p2 * yy + 1e-5f;
            float alpha = (1.f + 2.f * xy + yy) / dnm;   // coeff on (-P)
            float beta  = (1.f - p2) / dnm;              // coeff on X
            float num  = 2.f * (beta * xa - alpha * pa);
            float mob2 = alpha * alpha * p2 + beta * beta * yy
                       + 2.f * alpha * beta * xy;
            float den  = an * (1.f - mob2);
            out[(size_t)b * NN + n] = kk * fast_asinh(num / den);
        }
    }
}

extern "C" void kernel_launch(void* const* d_in, const int* in_sizes, int n_in,
                              void* d_out, int out_size, void* d_ws, size_t ws_size,
                              hipStream_t stream) {
    const float* x      = (const float*)d_in[0];
    const float* a_vals = (const float*)d_in[1];
    const float* p_vals = (const float*)d_in[2];
    float* out = (float*)d_out;

    ushort* Xf = (ushort*)d_ws;                 // [BB][DD] f16 (pre-swizzled)
    ushort* Pf = Xf + (size_t)BB * DD;          // [NN][DD] f16 (pre-swizzled)
    ushort* Af = Pf + (size_t)NN * DD;
    float*  y2  = (float*)(Af + (size_t)NN * DD);
    float*  p2s = y2 + BB;
    float*  pas = p2s + NN;
    float*  ans = pas + NN;
    float*  ks  = ans + NN;

    (void)hipFuncSetAttribute(reinterpret_cast<const void*>(hmlr_gemm),
                              hipFuncAttributeMaxDynamicSharedMemorySize, 98304);

    hipLaunchKernelGGL(hmlr_transform, dim3((BB + NN) / 4), dim3(256), 0, stream,
                       x, a_vals, p_vals, Xf, Pf, Af, y2, p2s, pas, ans, ks);
    hipLaunchKernelGGL(hmlr_gemm, dim3(256), dim3(512), 98304, stream,
                       Xf, Pf, Af, y2, p2s, pas, ans, ks, out);
}